// Round 6
// baseline (34.870 us; speedup 1.0000x reference)
//
#include <hip/hip_runtime.h>
#include <stdint.h>

// ACOLayer: reproduce JAX's sampling exactly.
//   u = jax.random.uniform(key(42), (32, 4096, 16), f32)
//   idx[b,i,a] = searchsorted(cdf_row_i, u[b,i,a]) clamped; -1 where a >= x[b,i]
// RNG: jax_threefry_partitionable=True stream:
//   bits[i] = o0 ^ o1, (o0,o1) = threefry2x32(key=(0,42), counter=(0, i))
//   u = bitcast((bits>>9)|0x3f800000) - 1.0f
// Round-6 structure: 1 row/block, FULLY-COALESCED weight loads (1KB/wave/instr,
// thread t owns float4 chunks at slots t+256i, i=0..3), component-wise float4
// wave scan + segment combine, x pre-transposed via d_ws to kill the 16KB-stride
// column read. Search: fixed 12-step lower_bound on unnormalized cumsum.

#define N_IN    4096
#define N_OUT   4096
#define BS      32
#define MAX_A   16
#define THREADS 256
#define HALF    1048576u  /* 16 * N_IN * MAX_A */

__device__ __forceinline__ uint32_t rotl32(uint32_t x, uint32_t r) {
    return (x << r) | (x >> (32u - r));
}

// Threefry-2x32, 20 rounds, key (0, 42) — jax.random.key(42)
__device__ __forceinline__ void threefry2x32_42(uint32_t x0, uint32_t x1,
                                                uint32_t& o0, uint32_t& o1) {
    const uint32_t k0 = 0u, k1 = 42u;
    const uint32_t k2 = k0 ^ k1 ^ 0x1BD11BDAu;
    x0 += k0; x1 += k1;
#define TF_R(r) { x0 += x1; x1 = rotl32(x1, (r)); x1 ^= x0; }
    TF_R(13) TF_R(15) TF_R(26) TF_R(6)
    x0 += k1; x1 += k2 + 1u;
    TF_R(17) TF_R(29) TF_R(16) TF_R(24)
    x0 += k2; x1 += k0 + 2u;
    TF_R(13) TF_R(15) TF_R(26) TF_R(6)
    x0 += k0; x1 += k1 + 3u;
    TF_R(17) TF_R(29) TF_R(16) TF_R(24)
    x0 += k1; x1 += k2 + 4u;
    TF_R(13) TF_R(15) TF_R(26) TF_R(6)
    x0 += k2; x1 += k0 + 5u;
#undef TF_R
    o0 = x0; o1 = x1;
}

__device__ __forceinline__ float bits_to_uniform(uint32_t b) {
    uint32_t f = (b >> 9) | 0x3f800000u;
    float r;
    __builtin_memcpy(&r, &f, 4);
    return r - 1.0f;
}

// fixed 12-step lower_bound on LDS cdf (no divergence)
__device__ __forceinline__ int lower_bound_cdf(const float* cdf, float tval) {
    int lo = 0, hi = N_OUT;
    #pragma unroll
    for (int it = 0; it < 12; ++it) {
        int mid = (lo + hi) >> 1;
        if (cdf[mid] < tval) lo = mid + 1; else hi = mid;
    }
    return lo < N_OUT ? lo : N_OUT - 1;
}

// x transpose: [32][4096] -> xT [4096][32]  (coalesced both sides via LDS tile)
__global__ __launch_bounds__(1024)
void transpose_x_kernel(const int* __restrict__ x, int* __restrict__ xT) {
    __shared__ int tile[32][33];
    const int i0 = blockIdx.x * 32;
    {
        const int b  = threadIdx.x >> 5;
        const int li = threadIdx.x & 31;
        tile[b][li] = x[b * N_IN + i0 + li];
    }
    __syncthreads();
    {
        const int i  = threadIdx.x >> 5;
        const int lb = threadIdx.x & 31;
        xT[(i0 + i) * 32 + lb] = tile[lb][i];
    }
}

template <bool USE_XT>
__global__ __launch_bounds__(THREADS)
void aco_sample_kernel(const int* __restrict__ xsrc,   // xT if USE_XT else x
                       const float* __restrict__ w,
                       int* __restrict__ out) {
    __shared__ float  cdf[N_OUT];
    __shared__ float4 wsum[4];
    __shared__ int    xc[BS];

    const int row  = blockIdx.x;
    const int t    = threadIdx.x;
    const int lane = t & 63;
    const int wid  = t >> 6;

    // ---- fully-coalesced weight loads: instr i = contiguous 4KB across block ----
    const float4* wrow4 = (const float4*)(w + (size_t)row * N_OUT);
    float4 v0 = wrow4[t];              // segment 0: floats 4t..4t+3
    float4 v1 = wrow4[t + 256];        // segment 1: floats 1024+4t..
    float4 v2 = wrow4[t + 512];
    float4 v3 = wrow4[t + 768];

    if (USE_XT) { if (t < BS) xc[t] = xsrc[row * BS + t]; }
    else        { if (t < BS) xc[t] = xsrc[t * N_IN + row]; }

    // ---- RNG in the load shadow (no dependence on loads) ----
    const int bb = t >> 4;
    const int aa = t & 15;
    const uint32_t j0 = (uint32_t)(bb * (N_IN * MAX_A) + row * MAX_A + aa);
    const uint32_t j1 = j0 + HALF;
    uint32_t o0, o1, p0, p1;
    threefry2x32_42(0u, j0, o0, o1);
    threefry2x32_42(0u, j1, p0, p1);
    const float u0 = bits_to_uniform(o0 ^ o1);
    const float u1 = bits_to_uniform(p0 ^ p1);

    // ---- per-chunk sums, component-wise float4 wave scan ----
    float4 s;
    s.x = v0.x + v0.y + v0.z + v0.w;
    s.y = v1.x + v1.y + v1.z + v1.w;
    s.z = v2.x + v2.y + v2.z + v2.w;
    s.w = v3.x + v3.y + v3.z + v3.w;

    float4 incl = s;
    #pragma unroll
    for (int d = 1; d < 64; d <<= 1) {
        float nx = __shfl_up(incl.x, d, 64);
        float ny = __shfl_up(incl.y, d, 64);
        float nz = __shfl_up(incl.z, d, 64);
        float nw = __shfl_up(incl.w, d, 64);
        if (lane >= d) { incl.x += nx; incl.y += ny; incl.z += nz; incl.w += nw; }
    }
    if (lane == 63) wsum[wid] = incl;
    __syncthreads();                     // B1: wave totals visible

    const float4 W0 = wsum[0], W1 = wsum[1], W2 = wsum[2], W3 = wsum[3];
    // segment totals
    const float T0 = W0.x + W1.x + W2.x + W3.x;
    const float T1 = W0.y + W1.y + W2.y + W3.y;
    const float T2 = W0.z + W1.z + W2.z + W3.z;
    const float T3 = W0.w + W1.w + W2.w + W3.w;
    const float total = T0 + T1 + T2 + T3;
    // per-segment wave prefixes for this wave
    float4 wp = make_float4(0.f, 0.f, 0.f, 0.f);
    if (wid > 0) { wp.x += W0.x; wp.y += W0.y; wp.z += W0.z; wp.w += W0.w; }
    if (wid > 1) { wp.x += W1.x; wp.y += W1.y; wp.z += W1.z; wp.w += W1.w; }
    if (wid > 2) { wp.x += W2.x; wp.y += W2.y; wp.z += W2.z; wp.w += W2.w; }
    // exclusive prefix per chunk: segment prefix + wave prefix + intra-wave excl
    const float E0 = 0.f            + wp.x + (incl.x - s.x);
    const float E1 = T0             + wp.y + (incl.y - s.y);
    const float E2 = T0 + T1        + wp.z + (incl.z - s.z);
    const float E3 = T0 + T1 + T2   + wp.w + (incl.w - s.w);

    // ---- write inclusive cumsum, float4 slot t+256i (contiguous per group) ----
    {
        float4 c;
        float r;
        r = E0 + v0.x; c.x = r; r += v0.y; c.y = r; r += v0.z; c.z = r; r += v0.w; c.w = r;
        ((float4*)cdf)[t] = c;
        r = E1 + v1.x; c.x = r; r += v1.y; c.y = r; r += v1.z; c.z = r; r += v1.w; c.w = r;
        ((float4*)cdf)[t + 256] = c;
        r = E2 + v2.x; c.x = r; r += v2.y; c.y = r; r += v2.z; c.z = r; r += v2.w; c.w = r;
        ((float4*)cdf)[t + 512] = c;
        r = E3 + v3.x; c.x = r; r += v3.y; c.y = r; r += v3.z; c.z = r; r += v3.w; c.w = r;
        ((float4*)cdf)[t + 768] = c;
    }
    __syncthreads();                     // B2: full cdf visible

    // ---- search + store ----
    const int idx0 = lower_bound_cdf(cdf, u0 * total);
    const int idx1 = lower_bound_cdf(cdf, u1 * total);
    out[j0] = (aa < xc[bb])      ? idx0 : -1;
    out[j1] = (aa < xc[bb + 16]) ? idx1 : -1;
}

extern "C" void kernel_launch(void* const* d_in, const int* in_sizes, int n_in,
                              void* d_out, int out_size, void* d_ws, size_t ws_size,
                              hipStream_t stream) {
    // select inputs by size (robust to ordering):
    //   x: 32*4096 int32; weights: 4096*4096 f32
    const int*   x;
    const float* w;
    if (in_sizes[0] == BS * N_IN) { x = (const int*)d_in[0]; w = (const float*)d_in[1]; }
    else                          { x = (const int*)d_in[1]; w = (const float*)d_in[0]; }
    int* out = (int*)d_out;

    const size_t xt_bytes = (size_t)N_IN * BS * sizeof(int);
    if (ws_size >= xt_bytes) {
        int* xT = (int*)d_ws;
        transpose_x_kernel<<<N_IN / 32, 1024, 0, stream>>>(x, xT);
        aco_sample_kernel<true><<<N_IN, THREADS, 0, stream>>>(xT, w, out);
    } else {
        aco_sample_kernel<false><<<N_IN, THREADS, 0, stream>>>(x, w, out);
    }
}